// Round 1
// baseline (248.237 us; speedup 1.0000x reference)
//
#include <hip/hip_runtime.h>
#include <hip/hip_bf16.h>
#include <stdint.h>

#define B_   8
#define DIM  1024
#define T_   2048
#define H_   16
#define HD   64

typedef __attribute__((ext_vector_type(8))) short bf16x8;
typedef __attribute__((ext_vector_type(4))) float f32x4;

__device__ __forceinline__ unsigned short f2bf(float f) {
    union { float f; unsigned u; } v{f};
    unsigned r = v.u + 0x7fffu + ((v.u >> 16) & 1u);   // RNE
    return (unsigned short)(r >> 16);
}

// async 16B/lane global->LDS; lds dest must be wave-uniform base (HW adds lane*16)
__device__ __forceinline__ void gl_lds16(const unsigned short* g, unsigned short* l) {
    __builtin_amdgcn_global_load_lds(
        (const __attribute__((address_space(1))) void*)(const void*)g,
        (__attribute__((address_space(3))) void*)(void*)l,
        16, 0, 0);
}

// Read one 16B MFMA fragment from a swizzled [rows][64] bf16 LDS tile.
// Physical 16B-block = logical_colgroup ^ (row&7).
__device__ __forceinline__ bf16x8 ld_frag(const unsigned short* smem, int row, int cg) {
    return *reinterpret_cast<const bf16x8*>(smem + row * 64 + (((cg) ^ (row & 7)) << 3));
}

// ---------------------------------------------------------------------------
// Kernel 1: x (B,DIM,T) f32  ->  XT (B,T,DIM) bf16   (transpose + cast)
// ---------------------------------------------------------------------------
__global__ void xpose_cast(const float* __restrict__ x, unsigned short* __restrict__ xt) {
    __shared__ float tile[64][65];
    const int b = blockIdx.z;
    const int d0 = blockIdx.y * 64, t0 = blockIdx.x * 64;
    const int tid = threadIdx.x;
    const int c = tid & 63;      // fast index (t on load, d on store)
    const int r0 = tid >> 6;     // 0..3

    const float* xp = x + ((size_t)b * DIM + d0) * T_ + t0;
#pragma unroll
    for (int i = 0; i < 16; ++i) {
        int r = r0 + i * 4;                       // d offset
        tile[r][c] = xp[(size_t)r * T_ + c];
    }
    __syncthreads();
    unsigned short* op = xt + ((size_t)b * T_ + t0) * DIM + d0;
#pragma unroll
    for (int i = 0; i < 16; ++i) {
        int r = r0 + i * 4;                       // t offset
        op[(size_t)r * DIM + c] = f2bf(tile[c][r]);
    }
}

// ---------------------------------------------------------------------------
// Kernel 2: cast w_in, w_out, toep_w to bf16
// ---------------------------------------------------------------------------
__global__ void cast_weights(const float* __restrict__ w_in, const float* __restrict__ w_out,
                             const float* __restrict__ tw,
                             unsigned short* __restrict__ w_in_b, unsigned short* __restrict__ w_out_b,
                             unsigned short* __restrict__ tw_b) {
    int i = blockIdx.x * 256 + threadIdx.x;
    if (i < DIM * DIM) {
        w_in_b[i]  = f2bf(w_in[i]);
        w_out_b[i] = f2bf(w_out[i]);
    }
    if (i < H_ * T_) tw_b[i] = f2bf(tw[i]);
}

// ---------------------------------------------------------------------------
// GEMM: Out_b(1024 x 2048) = W(1024x1024, bf16 row-major) @ B_b + bias
//   B-operand comes from a (B,T,DIM) bf16 tensor (rows t, k-contiguous).
//   Out layout (B,DIM,T): bf16 (OUT_BF16) or f32.
// 128x128 tile, BK=64, 4 waves (2x2 of 64x64), m97-style 2-barrier loop.
// ---------------------------------------------------------------------------
template <bool OUT_BF16>
__global__ void gemm_k(const unsigned short* __restrict__ Aw,   // (DIM,DIM) bf16
                       const unsigned short* __restrict__ Bm,   // (B,T,DIM) bf16
                       const float* __restrict__ bias,          // (DIM) f32
                       void* __restrict__ Out) {
    __shared__ __align__(16) unsigned short As[128 * 64];
    __shared__ __align__(16) unsigned short Bs[128 * 64];

    const int tid = threadIdx.x, lane = tid & 63, wv = tid >> 6;
    const int b = blockIdx.z;
    const int m0 = blockIdx.y * 128;     // rows (d)
    const int n0 = blockIdx.x * 128;     // cols (t)
    const unsigned short* Bb = Bm + (size_t)b * T_ * DIM;

    const int wr = wv >> 1, wc = wv & 1;
    const int lrow = lane & 15, lg = lane >> 4;

    f32x4 acc[4][4] = {};

    for (int k0 = 0; k0 < DIM; k0 += 64) {
        __syncthreads();
        // stage A (rows m0..m0+127 of Aw) and B (rows n0..n0+127 of Bb), 64 k each.
        // swizzle via pre-swizzled source: phys colgroup cg holds logical g = cg ^ (row&7)
#pragma unroll
        for (int it = 0; it < 4; ++it) {
            int ch = wv * 4 + it;                 // 1KiB chunk = 8 rows
            int r  = ch * 8 + (lane >> 3);
            int g  = (lane & 7) ^ (lane >> 3);
            gl_lds16(Aw + (size_t)(m0 + r) * DIM + k0 + g * 8, As + ch * 512);
            gl_lds16(Bb + (size_t)(n0 + r) * DIM + k0 + g * 8, Bs + ch * 512);
        }
        __syncthreads();

#pragma unroll
        for (int kk = 0; kk < 2; ++kk) {
            bf16x8 af[4], bfr[4];
#pragma unroll
            for (int mt = 0; mt < 4; ++mt) af[mt]  = ld_frag(As, wr * 64 + mt * 16 + lrow, kk * 4 + lg);
#pragma unroll
            for (int nt = 0; nt < 4; ++nt) bfr[nt] = ld_frag(Bs, wc * 64 + nt * 16 + lrow, kk * 4 + lg);
#pragma unroll
            for (int mt = 0; mt < 4; ++mt)
#pragma unroll
                for (int nt = 0; nt < 4; ++nt)
                    acc[mt][nt] = __builtin_amdgcn_mfma_f32_16x16x32_bf16(af[mt], bfr[nt], acc[mt][nt], 0, 0, 0);
        }
    }

    // epilogue: D row = (lane>>4)*4 + r, col = lane&15
    const size_t ob = (size_t)b * DIM * T_;
#pragma unroll
    for (int mt = 0; mt < 4; ++mt) {
        int d = m0 + wr * 64 + mt * 16 + lg * 4;
#pragma unroll
        for (int nt = 0; nt < 4; ++nt) {
            int t = n0 + wc * 64 + nt * 16 + lrow;
#pragma unroll
            for (int r = 0; r < 4; ++r) {
                float v = acc[mt][nt][r] + bias[d + r];
                if constexpr (OUT_BF16)
                    ((unsigned short*)Out)[ob + (size_t)(d + r) * T_ + t] = f2bf(v);
                else
                    ((float*)Out)[ob + (size_t)(d + r) * T_ + t] = v;
            }
        }
    }
}

// ---------------------------------------------------------------------------
// Conv: per (b, h, u-tile of 128): D[u][d] = sum_{t<=u} w[u-t]*H1[h*64+d][t] + tb[h][u]
// Computed as D = MT @ P  (MT[u][t] = M[t][u], generated in LDS from toep_w;
// P = H1 head-rows, staged k(t)-contiguous). Output C (B,T,DIM) bf16.
// 4 waves split the 128 u-rows (32 each), each wave covers all 64 d.
// ---------------------------------------------------------------------------
__global__ void conv_k(const unsigned short* __restrict__ H1,   // (B,DIM,T) bf16
                       const unsigned short* __restrict__ twb,  // (H,T) bf16
                       const float* __restrict__ tb,            // (H,T) f32
                       unsigned short* __restrict__ Cb) {       // (B,T,DIM) bf16
    __shared__ __align__(16) unsigned short Ms[128 * 64];  // MT[u][t] swizzled
    __shared__ __align__(16) unsigned short Ps[64 * 64];   // H1[d][t]  swizzled

    const int tid = threadIdx.x, lane = tid & 63, wv = tid >> 6;
    const int ut = (T_ / 128 - 1) - blockIdx.x;   // heavy tiles dispatched first
    const int h = blockIdx.y, b = blockIdx.z;
    const int u0 = ut * 128;
    const unsigned short* Hb = H1 + ((size_t)b * DIM + h * HD) * T_;

    const int lrow = lane & 15, lg = lane >> 4;
    const int mu = tid & 127;            // u row this thread generates
    const int gbase = (tid >> 7) * 4;

    f32x4 acc[2][4] = {};

    for (int t0 = 0; t0 <= u0 + 64; t0 += 64) {
        __syncthreads();
        // stage P: H1 rows d=0..63, cols t0..t0+63 (8 chunks of 8 rows)
#pragma unroll
        for (int it = 0; it < 2; ++it) {
            int ch = wv * 2 + it;
            int r  = ch * 8 + (lane >> 3);
            int g  = (lane & 7) ^ (lane >> 3);
            gl_lds16(Hb + (size_t)r * T_ + t0 + g * 8, Ps + ch * 512);
        }
        // generate MT[u][t] = (u>=t) ? w[u-t] : 0, swizzled like the A tiles
#pragma unroll
        for (int it = 0; it < 4; ++it) {
            int g = gbase + it;
            bf16x8 v;
#pragma unroll
            for (int j = 0; j < 8; ++j) {
                int lag = (u0 + mu) - (t0 + g * 8 + j);
                v[j] = (lag >= 0) ? (short)twb[h * T_ + lag] : (short)0;
            }
            *reinterpret_cast<bf16x8*>(Ms + mu * 64 + ((g ^ (mu & 7)) << 3)) = v;
        }
        __syncthreads();

#pragma unroll
        for (int kk = 0; kk < 2; ++kk) {
            bf16x8 af[2], bfr[4];
#pragma unroll
            for (int mt = 0; mt < 2; ++mt) af[mt]  = ld_frag(Ms, wv * 32 + mt * 16 + lrow, kk * 4 + lg);
#pragma unroll
            for (int nt = 0; nt < 4; ++nt) bfr[nt] = ld_frag(Ps, nt * 16 + lrow, kk * 4 + lg);
#pragma unroll
            for (int mt = 0; mt < 2; ++mt)
#pragma unroll
                for (int nt = 0; nt < 4; ++nt)
                    acc[mt][nt] = __builtin_amdgcn_mfma_f32_16x16x32_bf16(af[mt], bfr[nt], acc[mt][nt], 0, 0, 0);
        }
    }

    // epilogue -> C (B,T,DIM)
    const size_t cbase = (size_t)b * T_ * DIM + (size_t)h * HD;
#pragma unroll
    for (int mt = 0; mt < 2; ++mt) {
        int u = u0 + wv * 32 + mt * 16 + lg * 4;
#pragma unroll
        for (int nt = 0; nt < 4; ++nt) {
            int d = nt * 16 + lrow;
#pragma unroll
            for (int r = 0; r < 4; ++r) {
                float v = acc[mt][nt][r] + tb[h * T_ + u + r];
                Cb[cbase + (size_t)(u + r) * DIM + d] = f2bf(v);
            }
        }
    }
}

// ---------------------------------------------------------------------------
extern "C" void kernel_launch(void* const* d_in, const int* in_sizes, int n_in,
                              void* d_out, int out_size, void* d_ws, size_t ws_size,
                              hipStream_t stream) {
    (void)in_sizes; (void)n_in; (void)out_size; (void)ws_size;
    const float* x      = (const float*)d_in[0];
    const float* w_in   = (const float*)d_in[1];
    const float* b_in   = (const float*)d_in[2];
    const float* w_out  = (const float*)d_in[3];
    const float* b_out  = (const float*)d_in[4];
    const float* toep_w = (const float*)d_in[5];
    const float* toep_b = (const float*)d_in[6];

    char* ws = (char*)d_ws;
    unsigned short* XT    = (unsigned short*)(ws);                 // 32 MiB (B,T,DIM) bf16
    unsigned short* H1    = (unsigned short*)(ws + 33554432);      // 32 MiB (B,DIM,T) bf16
    unsigned short* Cbuf  = (unsigned short*)(ws + 67108864);      // 32 MiB (B,T,DIM) bf16
    unsigned short* winb  = (unsigned short*)(ws + 100663296);     // 2 MiB
    unsigned short* woutb = (unsigned short*)(ws + 102760448);     // 2 MiB
    unsigned short* twb   = (unsigned short*)(ws + 104857600);     // 64 KiB

    xpose_cast<<<dim3(T_ / 64, DIM / 64, B_), dim3(256), 0, stream>>>(x, XT);
    cast_weights<<<dim3((DIM * DIM) / 256), dim3(256), 0, stream>>>(w_in, w_out, toep_w, winb, woutb, twb);
    gemm_k<true><<<dim3(T_ / 128, DIM / 128, B_), dim3(256), 0, stream>>>(winb, XT, b_in, (void*)H1);
    conv_k<<<dim3(T_ / 128, H_, B_), dim3(256), 0, stream>>>(H1, twb, toep_b, Cbuf);
    gemm_k<false><<<dim3(T_ / 128, DIM / 128, B_), dim3(256), 0, stream>>>(woutb, Cbuf, b_out, d_out);
}

// Round 2
// 199.951 us; speedup vs baseline: 1.2415x; 1.2415x over previous
//
#include <hip/hip_runtime.h>
#include <hip/hip_bf16.h>
#include <stdint.h>

#define B_   8
#define DIM  1024
#define T_   2048
#define H_   16
#define HD   64

typedef __attribute__((ext_vector_type(8))) short bf16x8;
typedef __attribute__((ext_vector_type(4))) float f32x4;

__device__ __forceinline__ unsigned short f2bf(float f) {
    union { float f; unsigned u; } v{f};
    unsigned r = v.u + 0x7fffu + ((v.u >> 16) & 1u);   // RNE
    return (unsigned short)(r >> 16);
}

// async 16B/lane global->LDS; lds dest must be wave-uniform base (HW adds lane*16)
__device__ __forceinline__ void gl_lds16(const unsigned short* g, unsigned short* l) {
    __builtin_amdgcn_global_load_lds(
        (const __attribute__((address_space(1))) void*)(const void*)g,
        (__attribute__((address_space(3))) void*)(void*)l,
        16, 0, 0);
}

// Read one 16B MFMA fragment from a swizzled [rows][64] bf16 LDS tile.
// Physical 16B-block = logical_colgroup ^ (row&7).
__device__ __forceinline__ bf16x8 ld_frag(const unsigned short* smem, int row, int cg) {
    return *reinterpret_cast<const bf16x8*>(smem + row * 64 + (((cg) ^ (row & 7)) << 3));
}

// ---------------------------------------------------------------------------
// Kernel 1: x (B,DIM,T) f32  ->  XT (B,T,DIM) bf16   (transpose + cast)
// ---------------------------------------------------------------------------
__global__ void xpose_cast(const float* __restrict__ x, unsigned short* __restrict__ xt) {
    __shared__ float tile[64][65];
    const int b = blockIdx.z;
    const int d0 = blockIdx.y * 64, t0 = blockIdx.x * 64;
    const int tid = threadIdx.x;
    const int c = tid & 63;
    const int r0 = tid >> 6;

    const float* xp = x + ((size_t)b * DIM + d0) * T_ + t0;
#pragma unroll
    for (int i = 0; i < 16; ++i) {
        int r = r0 + i * 4;
        tile[r][c] = xp[(size_t)r * T_ + c];
    }
    __syncthreads();
    unsigned short* op = xt + ((size_t)b * T_ + t0) * DIM + d0;
#pragma unroll
    for (int i = 0; i < 16; ++i) {
        int r = r0 + i * 4;
        op[(size_t)r * DIM + c] = f2bf(tile[c][r]);
    }
}

// ---------------------------------------------------------------------------
// Kernel 2: cast w_in, w_out, toep_w to bf16
// ---------------------------------------------------------------------------
__global__ void cast_weights(const float* __restrict__ w_in, const float* __restrict__ w_out,
                             const float* __restrict__ tw,
                             unsigned short* __restrict__ w_in_b, unsigned short* __restrict__ w_out_b,
                             unsigned short* __restrict__ tw_b) {
    int i = blockIdx.x * 256 + threadIdx.x;
    if (i < DIM * DIM) {
        w_in_b[i]  = f2bf(w_in[i]);
        w_out_b[i] = f2bf(w_out[i]);
    }
    if (i < H_ * T_) tw_b[i] = f2bf(tw[i]);
}

// ---------------------------------------------------------------------------
// Kernel 3: build the 32 distinct diagonal M-tiles per head.
// Md[h][dg][u][j] = w[h][64*(dg-1) + u - j]  (0 if lag < 0),  dg in [0,32)
// 8 MiB total -> L2/LLC resident for conv2_k.
// ---------------------------------------------------------------------------
__global__ void gen_mdiag(const unsigned short* __restrict__ twb, unsigned short* __restrict__ Md) {
    const int h = blockIdx.y, dg = blockIdx.x;
    const int D = (dg - 1) * 64;
    unsigned short* out = Md + (((size_t)h * 32 + dg) << 13);
    for (int v = threadIdx.x; v < 1024; v += 256) {
        int u = v >> 3, j0 = (v & 7) * 8;
        bf16x8 w;
#pragma unroll
        for (int j = 0; j < 8; ++j) {
            int lag = D + u - (j0 + j);
            w[j] = (lag >= 0) ? (short)twb[h * T_ + lag] : (short)0;
        }
        *reinterpret_cast<bf16x8*>(out + v * 8) = w;
    }
}

// ---------------------------------------------------------------------------
// GEMM: Out_b(1024 x 2048) = W(1024x1024, bf16 row-major) @ B_b + bias
// 128x128 tile, BK=64, 4 waves (2x2 of 64x64), m97-style 2-barrier loop.
// ---------------------------------------------------------------------------
template <bool OUT_BF16>
__global__ void gemm_k(const unsigned short* __restrict__ Aw,   // (DIM,DIM) bf16
                       const unsigned short* __restrict__ Bm,   // (B,T,DIM) bf16
                       const float* __restrict__ bias,          // (DIM) f32
                       void* __restrict__ Out) {
    __shared__ __align__(16) unsigned short As[128 * 64];
    __shared__ __align__(16) unsigned short Bs[128 * 64];

    const int tid = threadIdx.x, lane = tid & 63, wv = tid >> 6;
    const int b = blockIdx.z;
    const int m0 = blockIdx.y * 128;
    const int n0 = blockIdx.x * 128;
    const unsigned short* Bb = Bm + (size_t)b * T_ * DIM;

    const int wr = wv >> 1, wc = wv & 1;
    const int lrow = lane & 15, lg = lane >> 4;

    f32x4 acc[4][4] = {};

    for (int k0 = 0; k0 < DIM; k0 += 64) {
        __syncthreads();
#pragma unroll
        for (int it = 0; it < 4; ++it) {
            int ch = wv * 4 + it;
            int r  = ch * 8 + (lane >> 3);
            int g  = (lane & 7) ^ (lane >> 3);
            gl_lds16(Aw + (size_t)(m0 + r) * DIM + k0 + g * 8, As + ch * 512);
            gl_lds16(Bb + (size_t)(n0 + r) * DIM + k0 + g * 8, Bs + ch * 512);
        }
        __syncthreads();

#pragma unroll
        for (int kk = 0; kk < 2; ++kk) {
            bf16x8 af[4], bfr[4];
#pragma unroll
            for (int mt = 0; mt < 4; ++mt) af[mt]  = ld_frag(As, wr * 64 + mt * 16 + lrow, kk * 4 + lg);
#pragma unroll
            for (int nt = 0; nt < 4; ++nt) bfr[nt] = ld_frag(Bs, wc * 64 + nt * 16 + lrow, kk * 4 + lg);
#pragma unroll
            for (int mt = 0; mt < 4; ++mt)
#pragma unroll
                for (int nt = 0; nt < 4; ++nt)
                    acc[mt][nt] = __builtin_amdgcn_mfma_f32_16x16x32_bf16(af[mt], bfr[nt], acc[mt][nt], 0, 0, 0);
        }
    }

    const size_t ob = (size_t)b * DIM * T_;
#pragma unroll
    for (int mt = 0; mt < 4; ++mt) {
        int d = m0 + wr * 64 + mt * 16 + lg * 4;
#pragma unroll
        for (int nt = 0; nt < 4; ++nt) {
            int t = n0 + wc * 64 + nt * 16 + lrow;
#pragma unroll
            for (int r = 0; r < 4; ++r) {
                float v = acc[mt][nt][r] + bias[d + r];
                if constexpr (OUT_BF16)
                    ((unsigned short*)Out)[ob + (size_t)(d + r) * T_ + t] = f2bf(v);
                else
                    ((float*)Out)[ob + (size_t)(d + r) * T_ + t] = v;
            }
        }
    }
}

// ---------------------------------------------------------------------------
// Conv v2: pure GEMM. Per (u-tile, h, batch-pair):
//   D[u][(b,d)] = sum_t Md[h][dg(kt)][u][t] * H1[b][h*64+d][t0+t]
// A-tile selected by diagonal index (L2-resident), B = two H1 head-slabs.
// Output tile 128 x 128, 4 waves (32u x 128 cols each), acc[2][8].
// ---------------------------------------------------------------------------
__global__ void conv2_k(const unsigned short* __restrict__ H1,   // (B,DIM,T) bf16
                        const unsigned short* __restrict__ Md,   // (H,32,128,64) bf16
                        const float* __restrict__ tb,            // (H,T) f32
                        unsigned short* __restrict__ Cb) {       // (B,T,DIM) bf16
    __shared__ __align__(16) unsigned short As[128 * 64];
    __shared__ __align__(16) unsigned short Ps[128 * 64];

    const int tid = threadIdx.x, lane = tid & 63, wv = tid >> 6;
    const int ut = (T_ / 128 - 1) - blockIdx.x;   // heavy tiles first
    const int h  = blockIdx.y;
    const int b0 = blockIdx.z * 2;
    const int u0 = ut * 128;
    const unsigned short* Hb0 = H1 + ((size_t)b0 * DIM + h * HD) * T_;
    const unsigned short* Hb1 = H1 + ((size_t)(b0 + 1) * DIM + h * HD) * T_;

    const int lrow = lane & 15, lg = lane >> 4;
    const int rsub = lane >> 3;
    const int g = (lane & 7) ^ rsub;

    f32x4 acc[2][8] = {};

    const int nk = 2 * ut + 2;
    for (int kt = 0; kt < nk; ++kt) {
        const int t0 = kt * 64;
        const int dg = 2 * ut - kt + 1;
        const unsigned short* At = Md + (((size_t)h * 32 + dg) << 13);
        __syncthreads();
#pragma unroll
        for (int it = 0; it < 4; ++it) {
            int ch = wv * 4 + it;
            int r  = ch * 8 + rsub;
            gl_lds16(At + (size_t)r * 64 + g * 8, As + ch * 512);
            const unsigned short* src = (r < 64)
                ? (Hb0 + (size_t)r * T_ + t0 + g * 8)
                : (Hb1 + (size_t)(r - 64) * T_ + t0 + g * 8);
            gl_lds16(src, Ps + ch * 512);
        }
        __syncthreads();

#pragma unroll
        for (int kk = 0; kk < 2; ++kk) {
            bf16x8 af[2], bfr[8];
#pragma unroll
            for (int mt = 0; mt < 2; ++mt) af[mt]  = ld_frag(As, wv * 32 + mt * 16 + lrow, kk * 4 + lg);
#pragma unroll
            for (int nt = 0; nt < 8; ++nt) bfr[nt] = ld_frag(Ps, nt * 16 + lrow, kk * 4 + lg);
#pragma unroll
            for (int mt = 0; mt < 2; ++mt)
#pragma unroll
                for (int nt = 0; nt < 8; ++nt)
                    acc[mt][nt] = __builtin_amdgcn_mfma_f32_16x16x32_bf16(af[mt], bfr[nt], acc[mt][nt], 0, 0, 0);
        }
    }

    // epilogue -> C (B,T,DIM):  row u from A, col (b,d) from Ps rows
#pragma unroll
    for (int mt = 0; mt < 2; ++mt) {
        int u = u0 + wv * 32 + mt * 16 + lg * 4;
#pragma unroll
        for (int nt = 0; nt < 8; ++nt) {
            int col = nt * 16 + lrow;
            int b   = b0 + (col >> 6);
            int d   = col & 63;
            size_t base = (size_t)b * T_ * DIM + (size_t)h * HD + d;
#pragma unroll
            for (int r = 0; r < 4; ++r) {
                float v = acc[mt][nt][r] + tb[h * T_ + u + r];
                Cb[base + (size_t)(u + r) * DIM] = f2bf(v);
            }
        }
    }
}

// ---------------------------------------------------------------------------
extern "C" void kernel_launch(void* const* d_in, const int* in_sizes, int n_in,
                              void* d_out, int out_size, void* d_ws, size_t ws_size,
                              hipStream_t stream) {
    (void)in_sizes; (void)n_in; (void)out_size; (void)ws_size;
    const float* x      = (const float*)d_in[0];
    const float* w_in   = (const float*)d_in[1];
    const float* b_in   = (const float*)d_in[2];
    const float* w_out  = (const float*)d_in[3];
    const float* b_out  = (const float*)d_in[4];
    const float* toep_w = (const float*)d_in[5];
    const float* toep_b = (const float*)d_in[6];

    char* ws = (char*)d_ws;
    unsigned short* XT    = (unsigned short*)(ws);                 // 32 MiB (B,T,DIM) bf16
    unsigned short* H1    = (unsigned short*)(ws + 33554432);      // 32 MiB (B,DIM,T) bf16
    unsigned short* Cbuf  = (unsigned short*)(ws + 67108864);      // 32 MiB (B,T,DIM) bf16
    unsigned short* winb  = (unsigned short*)(ws + 100663296);     // 2 MiB
    unsigned short* woutb = (unsigned short*)(ws + 102760448);     // 2 MiB
    unsigned short* twb   = (unsigned short*)(ws + 104857600);     // 64 KiB
    unsigned short* Mdiag = (unsigned short*)(ws + 104923136);     // 8 MiB (H,32,128,64)

    xpose_cast<<<dim3(T_ / 64, DIM / 64, B_), dim3(256), 0, stream>>>(x, XT);
    cast_weights<<<dim3((DIM * DIM) / 256), dim3(256), 0, stream>>>(w_in, w_out, toep_w, winb, woutb, twb);
    gen_mdiag<<<dim3(32, H_), dim3(256), 0, stream>>>(twb, Mdiag);
    gemm_k<true><<<dim3(T_ / 128, DIM / 128, B_), dim3(256), 0, stream>>>(winb, XT, b_in, (void*)H1);
    conv2_k<<<dim3(T_ / 128, H_, B_ / 2), dim3(256), 0, stream>>>(H1, Mdiag, toep_b, Cbuf);
    gemm_k<false><<<dim3(T_ / 128, DIM / 128, B_), dim3(256), 0, stream>>>(woutb, Cbuf, b_out, d_out);
}

// Round 3
// 174.277 us; speedup vs baseline: 1.4244x; 1.1473x over previous
//
#include <hip/hip_runtime.h>
#include <hip/hip_bf16.h>
#include <stdint.h>

#define B_   8
#define DIM  1024
#define T_   2048
#define H_   16
#define HD   64

typedef __attribute__((ext_vector_type(8))) short bf16x8;
typedef __attribute__((ext_vector_type(4))) float f32x4;

__device__ __forceinline__ unsigned short f2bf(float f) {
    union { float f; unsigned u; } v{f};
    unsigned r = v.u + 0x7fffu + ((v.u >> 16) & 1u);   // RNE
    return (unsigned short)(r >> 16);
}

// async 16B/lane global->LDS; lds dest must be wave-uniform base (HW adds lane*16)
__device__ __forceinline__ void gl_lds16(const unsigned short* g, unsigned short* l) {
    __builtin_amdgcn_global_load_lds(
        (const __attribute__((address_space(1))) void*)(const void*)g,
        (__attribute__((address_space(3))) void*)(void*)l,
        16, 0, 0);
}

// Read one 16B MFMA fragment from a swizzled [rows][64] bf16 LDS tile.
// Physical 16B-block = logical_colgroup ^ (row&7).
__device__ __forceinline__ bf16x8 ld_frag(const unsigned short* smem, int row, int cg) {
    return *reinterpret_cast<const bf16x8*>(smem + row * 64 + (((cg) ^ (row & 7)) << 3));
}

// ---------------------------------------------------------------------------
// Kernel 1: x (B,DIM,T) f32  ->  XT (B,T,DIM) bf16   (transpose + cast)
// ---------------------------------------------------------------------------
__global__ void xpose_cast(const float* __restrict__ x, unsigned short* __restrict__ xt) {
    __shared__ float tile[64][65];
    const int b = blockIdx.z;
    const int d0 = blockIdx.y * 64, t0 = blockIdx.x * 64;
    const int tid = threadIdx.x;
    const int c = tid & 63;
    const int r0 = tid >> 6;

    const float* xp = x + ((size_t)b * DIM + d0) * T_ + t0;
#pragma unroll
    for (int i = 0; i < 16; ++i) {
        int r = r0 + i * 4;
        tile[r][c] = xp[(size_t)r * T_ + c];
    }
    __syncthreads();
    unsigned short* op = xt + ((size_t)b * T_ + t0) * DIM + d0;
#pragma unroll
    for (int i = 0; i < 16; ++i) {
        int r = r0 + i * 4;
        op[(size_t)r * DIM + c] = f2bf(tile[c][r]);
    }
}

// ---------------------------------------------------------------------------
// Kernel 2: cast w_in, w_out, toep_w to bf16
// ---------------------------------------------------------------------------
__global__ void cast_weights(const float* __restrict__ w_in, const float* __restrict__ w_out,
                             const float* __restrict__ tw,
                             unsigned short* __restrict__ w_in_b, unsigned short* __restrict__ w_out_b,
                             unsigned short* __restrict__ tw_b) {
    int i = blockIdx.x * 256 + threadIdx.x;
    if (i < DIM * DIM) {
        w_in_b[i]  = f2bf(w_in[i]);
        w_out_b[i] = f2bf(w_out[i]);
    }
    if (i < H_ * T_) tw_b[i] = f2bf(tw[i]);
}

// ---------------------------------------------------------------------------
// Kernel 3: build the 32 distinct diagonal M-tiles per head.
// Md[h][dg][u][j] = w[h][64*(dg-1) + u - j]  (0 if lag < 0),  dg in [0,32)
// 8 MiB total -> L2/LLC resident for conv.
// ---------------------------------------------------------------------------
__global__ void gen_mdiag(const unsigned short* __restrict__ twb, unsigned short* __restrict__ Md) {
    const int h = blockIdx.y, dg = blockIdx.x;
    const int D = (dg - 1) * 64;
    unsigned short* out = Md + (((size_t)h * 32 + dg) << 13);
    for (int v = threadIdx.x; v < 1024; v += 256) {
        int u = v >> 3, j0 = (v & 7) * 8;
        bf16x8 w;
#pragma unroll
        for (int j = 0; j < 8; ++j) {
            int lag = D + u - (j0 + j);
            w[j] = (lag >= 0) ? (short)twb[h * T_ + lag] : (short)0;
        }
        *reinterpret_cast<bf16x8*>(out + v * 8) = w;
    }
}

// ---------------------------------------------------------------------------
// GEMM: Out_b(1024 x 2048) = W(1024x1024, bf16 row-major) @ B_b + bias
// 128x128 tile, BK=64, 4 waves (2x2 of 64x64), m97-style 2-barrier loop.
// ---------------------------------------------------------------------------
template <bool OUT_BF16>
__global__ void gemm_k(const unsigned short* __restrict__ Aw,   // (DIM,DIM) bf16
                       const unsigned short* __restrict__ Bm,   // (B,T,DIM) bf16
                       const float* __restrict__ bias,          // (DIM) f32
                       void* __restrict__ Out) {
    __shared__ __align__(16) unsigned short As[128 * 64];
    __shared__ __align__(16) unsigned short Bs[128 * 64];

    const int tid = threadIdx.x, lane = tid & 63, wv = tid >> 6;
    const int b = blockIdx.z;
    const int m0 = blockIdx.y * 128;
    const int n0 = blockIdx.x * 128;
    const unsigned short* Bb = Bm + (size_t)b * T_ * DIM;

    const int wr = wv >> 1, wc = wv & 1;
    const int lrow = lane & 15, lg = lane >> 4;

    f32x4 acc[4][4] = {};

    for (int k0 = 0; k0 < DIM; k0 += 64) {
        __syncthreads();
#pragma unroll
        for (int it = 0; it < 4; ++it) {
            int ch = wv * 4 + it;
            int r  = ch * 8 + (lane >> 3);
            int g  = (lane & 7) ^ (lane >> 3);
            gl_lds16(Aw + (size_t)(m0 + r) * DIM + k0 + g * 8, As + ch * 512);
            gl_lds16(Bb + (size_t)(n0 + r) * DIM + k0 + g * 8, Bs + ch * 512);
        }
        __syncthreads();

#pragma unroll
        for (int kk = 0; kk < 2; ++kk) {
            bf16x8 af[4], bfr[4];
#pragma unroll
            for (int mt = 0; mt < 4; ++mt) af[mt]  = ld_frag(As, wr * 64 + mt * 16 + lrow, kk * 4 + lg);
#pragma unroll
            for (int nt = 0; nt < 4; ++nt) bfr[nt] = ld_frag(Bs, wc * 64 + nt * 16 + lrow, kk * 4 + lg);
#pragma unroll
            for (int mt = 0; mt < 4; ++mt)
#pragma unroll
                for (int nt = 0; nt < 4; ++nt)
                    acc[mt][nt] = __builtin_amdgcn_mfma_f32_16x16x32_bf16(af[mt], bfr[nt], acc[mt][nt], 0, 0, 0);
        }
    }

    const size_t ob = (size_t)b * DIM * T_;
#pragma unroll
    for (int mt = 0; mt < 4; ++mt) {
        int d = m0 + wr * 64 + mt * 16 + lg * 4;
#pragma unroll
        for (int nt = 0; nt < 4; ++nt) {
            int t = n0 + wc * 64 + nt * 16 + lrow;
#pragma unroll
            for (int r = 0; r < 4; ++r) {
                float v = acc[mt][nt][r] + bias[d + r];
                if constexpr (OUT_BF16)
                    ((unsigned short*)Out)[ob + (size_t)(d + r) * T_ + t] = f2bf(v);
                else
                    ((float*)Out)[ob + (size_t)(d + r) * T_ + t] = v;
            }
        }
    }
}

// ---------------------------------------------------------------------------
// Conv v3: balanced triangular GEMM.
// Each block: one (h, b), a PAIR of u-tiles {15-bx, bx} -> exactly 34 K-steps.
// Per u-tile phase: D[u][d] = sum_t Md[h][dg][u][t] * H1[b][h*64+d][t0+t]
// Output tile 128u x 64d, 4 waves (32u x 64d each), acc[2][4].
// ---------------------------------------------------------------------------
__global__ void conv3_k(const unsigned short* __restrict__ H1,   // (B,DIM,T) bf16
                        const unsigned short* __restrict__ Md,   // (H,32,128,64) bf16
                        const float* __restrict__ tb,            // (H,T) f32
                        unsigned short* __restrict__ Cb) {       // (B,T,DIM) bf16
    __shared__ __align__(16) unsigned short As[128 * 64];
    __shared__ __align__(16) unsigned short Ps[64 * 64];

    const int tid = threadIdx.x, lane = tid & 63, wv = tid >> 6;
    const int h = blockIdx.y;
    const int b = blockIdx.z;
    const unsigned short* Hb = H1 + ((size_t)b * DIM + h * HD) * T_;

    const int lrow = lane & 15, lg = lane >> 4;
    const int rsub = lane >> 3;
    const int g = (lane & 7) ^ rsub;

#pragma unroll
    for (int ph = 0; ph < 2; ++ph) {
        const int ut = ph ? blockIdx.x : (T_ / 128 - 1 - blockIdx.x);
        const int u0 = ut * 128;
        f32x4 acc[2][4] = {};

        const int nk = 2 * ut + 2;
        for (int kt = 0; kt < nk; ++kt) {
            const int t0 = kt * 64;
            const int dg = 2 * ut - kt + 1;
            const unsigned short* At = Md + (((size_t)h * 32 + dg) << 13);
            __syncthreads();
#pragma unroll
            for (int it = 0; it < 4; ++it) {            // A: 16 chunks of 8 rows
                int ch = wv * 4 + it;
                int r  = ch * 8 + rsub;
                gl_lds16(At + (size_t)r * 64 + g * 8, As + ch * 512);
            }
#pragma unroll
            for (int it = 0; it < 2; ++it) {            // P: 8 chunks of 8 rows
                int ch = wv * 2 + it;
                int r  = ch * 8 + rsub;
                gl_lds16(Hb + (size_t)r * T_ + t0 + g * 8, Ps + ch * 512);
            }
            __syncthreads();

#pragma unroll
            for (int kk = 0; kk < 2; ++kk) {
                bf16x8 af[2], bfr[4];
#pragma unroll
                for (int mt = 0; mt < 2; ++mt) af[mt]  = ld_frag(As, wv * 32 + mt * 16 + lrow, kk * 4 + lg);
#pragma unroll
                for (int nt = 0; nt < 4; ++nt) bfr[nt] = ld_frag(Ps, nt * 16 + lrow, kk * 4 + lg);
#pragma unroll
                for (int mt = 0; mt < 2; ++mt)
#pragma unroll
                    for (int nt = 0; nt < 4; ++nt)
                        acc[mt][nt] = __builtin_amdgcn_mfma_f32_16x16x32_bf16(af[mt], bfr[nt], acc[mt][nt], 0, 0, 0);
            }
        }

        // epilogue -> C (B,T,DIM)
        const size_t base = (size_t)b * T_ * DIM + (size_t)h * HD;
#pragma unroll
        for (int mt = 0; mt < 2; ++mt) {
            int u = u0 + wv * 32 + mt * 16 + lg * 4;
            const float* tbp = tb + h * T_ + u;
            float t0v = tbp[0], t1v = tbp[1], t2v = tbp[2], t3v = tbp[3];
#pragma unroll
            for (int nt = 0; nt < 4; ++nt) {
                int d = nt * 16 + lrow;
                size_t p = base + (size_t)u * DIM + d;
                Cb[p]           = f2bf(acc[mt][nt][0] + t0v);
                Cb[p + DIM]     = f2bf(acc[mt][nt][1] + t1v);
                Cb[p + 2 * DIM] = f2bf(acc[mt][nt][2] + t2v);
                Cb[p + 3 * DIM] = f2bf(acc[mt][nt][3] + t3v);
            }
        }
    }
}

// ---------------------------------------------------------------------------
extern "C" void kernel_launch(void* const* d_in, const int* in_sizes, int n_in,
                              void* d_out, int out_size, void* d_ws, size_t ws_size,
                              hipStream_t stream) {
    (void)in_sizes; (void)n_in; (void)out_size; (void)ws_size;
    const float* x      = (const float*)d_in[0];
    const float* w_in   = (const float*)d_in[1];
    const float* b_in   = (const float*)d_in[2];
    const float* w_out  = (const float*)d_in[3];
    const float* b_out  = (const float*)d_in[4];
    const float* toep_w = (const float*)d_in[5];
    const float* toep_b = (const float*)d_in[6];

    char* ws = (char*)d_ws;
    unsigned short* XT    = (unsigned short*)(ws);                 // 32 MiB (B,T,DIM) bf16
    unsigned short* H1    = (unsigned short*)(ws + 33554432);      // 32 MiB (B,DIM,T) bf16
    unsigned short* Cbuf  = (unsigned short*)(ws + 67108864);      // 32 MiB (B,T,DIM) bf16
    unsigned short* winb  = (unsigned short*)(ws + 100663296);     // 2 MiB
    unsigned short* woutb = (unsigned short*)(ws + 102760448);     // 2 MiB
    unsigned short* twb   = (unsigned short*)(ws + 104857600);     // 64 KiB
    unsigned short* Mdiag = (unsigned short*)(ws + 104923136);     // 8 MiB (H,32,128,64)

    xpose_cast<<<dim3(T_ / 64, DIM / 64, B_), dim3(256), 0, stream>>>(x, XT);
    cast_weights<<<dim3((DIM * DIM) / 256), dim3(256), 0, stream>>>(w_in, w_out, toep_w, winb, woutb, twb);
    gen_mdiag<<<dim3(32, H_), dim3(256), 0, stream>>>(twb, Mdiag);
    gemm_k<true><<<dim3(T_ / 128, DIM / 128, B_), dim3(256), 0, stream>>>(winb, XT, b_in, (void*)H1);
    conv3_k<<<dim3(T_ / 256, H_, B_), dim3(256), 0, stream>>>(H1, Mdiag, toep_b, Cbuf);
    gemm_k<false><<<dim3(T_ / 128, DIM / 128, B_), dim3(256), 0, stream>>>(woutb, Cbuf, b_out, d_out);
}

// Round 4
// 145.255 us; speedup vs baseline: 1.7090x; 1.1998x over previous
//
#include <hip/hip_runtime.h>
#include <hip/hip_bf16.h>
#include <stdint.h>

#define B_   8
#define DIM  1024
#define T_   2048
#define H_   16
#define HD   64

typedef __attribute__((ext_vector_type(8))) short bf16x8;
typedef __attribute__((ext_vector_type(4))) float f32x4;

__device__ __forceinline__ unsigned short f2bf(float f) {
    union { float f; unsigned u; } v{f};
    unsigned r = v.u + 0x7fffu + ((v.u >> 16) & 1u);   // RNE
    return (unsigned short)(r >> 16);
}

// async 16B/lane global->LDS; lds dest must be wave-uniform base (HW adds lane*16)
__device__ __forceinline__ void gl_lds16(const unsigned short* g, unsigned short* l) {
    __builtin_amdgcn_global_load_lds(
        (const __attribute__((address_space(1))) void*)(const void*)g,
        (__attribute__((address_space(3))) void*)(void*)l,
        16, 0, 0);
}

// Read one 16B MFMA fragment from a swizzled [rows][64] bf16 LDS tile.
// Physical 16B-block = logical_colgroup ^ (row&7).
__device__ __forceinline__ bf16x8 ld_frag(const unsigned short* smem, int row, int cg) {
    return *reinterpret_cast<const bf16x8*>(smem + row * 64 + (((cg) ^ (row & 7)) << 3));
}

// ---------------------------------------------------------------------------
// Kernel 1: x (B,DIM,T) f32  ->  XT (B,T,DIM) bf16   (transpose + cast)
// ---------------------------------------------------------------------------
__global__ void xpose_cast(const float* __restrict__ x, unsigned short* __restrict__ xt) {
    __shared__ float tile[64][65];
    const int b = blockIdx.z;
    const int d0 = blockIdx.y * 64, t0 = blockIdx.x * 64;
    const int tid = threadIdx.x;
    const int c = tid & 63;
    const int r0 = tid >> 6;

    const float* xp = x + ((size_t)b * DIM + d0) * T_ + t0;
#pragma unroll
    for (int i = 0; i < 16; ++i) {
        int r = r0 + i * 4;
        tile[r][c] = xp[(size_t)r * T_ + c];
    }
    __syncthreads();
    unsigned short* op = xt + ((size_t)b * T_ + t0) * DIM + d0;
#pragma unroll
    for (int i = 0; i < 16; ++i) {
        int r = r0 + i * 4;
        op[(size_t)r * DIM + c] = f2bf(tile[c][r]);
    }
}

// ---------------------------------------------------------------------------
// Kernel 2: cast w_in, w_out, toep_w to bf16
// ---------------------------------------------------------------------------
__global__ void cast_weights(const float* __restrict__ w_in, const float* __restrict__ w_out,
                             const float* __restrict__ tw,
                             unsigned short* __restrict__ w_in_b, unsigned short* __restrict__ w_out_b,
                             unsigned short* __restrict__ tw_b) {
    int i = blockIdx.x * 256 + threadIdx.x;
    if (i < DIM * DIM) {
        w_in_b[i]  = f2bf(w_in[i]);
        w_out_b[i] = f2bf(w_out[i]);
    }
    if (i < H_ * T_) tw_b[i] = f2bf(tw[i]);
}

// ---------------------------------------------------------------------------
// Kernel 3: build diagonal M-tiles in MFMA *fragment* layout:
// Mf[h][dg][cg][row][j] = w[h][ 64*(dg-1) + row - (cg*8+j) ]  (0 if lag<0)
//   cg in [0,8) (k col-group of 8), row in [0,128).  8 MiB total, L2-resident.
// A wave's fragment read (fixed cg, 16 consecutive rows) = contiguous 256B.
// ---------------------------------------------------------------------------
__global__ void gen_mfrag(const unsigned short* __restrict__ twb, unsigned short* __restrict__ Mf) {
    const int h = blockIdx.y, dg = blockIdx.x;
    const int D = (dg - 1) * 64;
    unsigned short* out = Mf + (((size_t)h * 32 + dg) << 13);   // 8192 elems per (h,dg)
    for (int v = threadIdx.x; v < 1024; v += 256) {
        int cg = v >> 7, row = v & 127;
        bf16x8 w;
#pragma unroll
        for (int j = 0; j < 8; ++j) {
            int lag = D + row - (cg * 8 + j);
            w[j] = (lag >= 0) ? (short)twb[h * T_ + lag] : (short)0;
        }
        *reinterpret_cast<bf16x8*>(out + (size_t)v * 8) = w;
    }
}

// ---------------------------------------------------------------------------
// GEMM: Out_b(1024 x 2048) = W(1024x1024, bf16 row-major) @ B_b + bias
// 128x128 tile, BK=64, 4 waves (2x2 of 64x64). 1-D grid + chunked XCD swizzle
// (each XCD owns one batch -> A 2MB + B(b) 4MB ~ L2-resident).
// ---------------------------------------------------------------------------
template <bool OUT_BF16>
__global__ void gemm_k(const unsigned short* __restrict__ Aw,   // (DIM,DIM) bf16
                       const unsigned short* __restrict__ Bm,   // (B,T,DIM) bf16
                       const float* __restrict__ bias,          // (DIM) f32
                       void* __restrict__ Out) {
    __shared__ __align__(16) unsigned short As[128 * 64];
    __shared__ __align__(16) unsigned short Bs[128 * 64];

    const int flat = blockIdx.x;                 // 1024 blocks
    const int wid  = (flat & 7) * 128 + (flat >> 3);
    const int nx   = wid & 15;
    const int my   = (wid >> 4) & 7;
    const int b    = wid >> 7;

    const int tid = threadIdx.x, lane = tid & 63, wv = tid >> 6;
    const int m0 = my * 128;
    const int n0 = nx * 128;
    const unsigned short* Bb = Bm + (size_t)b * T_ * DIM;

    const int wr = wv >> 1, wc = wv & 1;
    const int lrow = lane & 15, lg = lane >> 4;

    f32x4 acc[4][4] = {};

    for (int k0 = 0; k0 < DIM; k0 += 64) {
        __syncthreads();
#pragma unroll
        for (int it = 0; it < 4; ++it) {
            int ch = wv * 4 + it;
            int r  = ch * 8 + (lane >> 3);
            int g  = (lane & 7) ^ (lane >> 3);
            gl_lds16(Aw + (size_t)(m0 + r) * DIM + k0 + g * 8, As + ch * 512);
            gl_lds16(Bb + (size_t)(n0 + r) * DIM + k0 + g * 8, Bs + ch * 512);
        }
        __syncthreads();

#pragma unroll
        for (int kk = 0; kk < 2; ++kk) {
            bf16x8 af[4], bfr[4];
#pragma unroll
            for (int mt = 0; mt < 4; ++mt) af[mt]  = ld_frag(As, wr * 64 + mt * 16 + lrow, kk * 4 + lg);
#pragma unroll
            for (int nt = 0; nt < 4; ++nt) bfr[nt] = ld_frag(Bs, wc * 64 + nt * 16 + lrow, kk * 4 + lg);
#pragma unroll
            for (int mt = 0; mt < 4; ++mt)
#pragma unroll
                for (int nt = 0; nt < 4; ++nt)
                    acc[mt][nt] = __builtin_amdgcn_mfma_f32_16x16x32_bf16(af[mt], bfr[nt], acc[mt][nt], 0, 0, 0);
        }
    }

    const size_t ob = (size_t)b * DIM * T_;
#pragma unroll
    for (int mt = 0; mt < 4; ++mt) {
        int d = m0 + wr * 64 + mt * 16 + lg * 4;
#pragma unroll
        for (int nt = 0; nt < 4; ++nt) {
            int t = n0 + wc * 64 + nt * 16 + lrow;
#pragma unroll
            for (int r = 0; r < 4; ++r) {
                float v = acc[mt][nt][r] + bias[d + r];
                if constexpr (OUT_BF16)
                    ((unsigned short*)Out)[ob + (size_t)(d + r) * T_ + t] = f2bf(v);
                else
                    ((float*)Out)[ob + (size_t)(d + r) * T_ + t] = v;
            }
        }
    }
}

// ---------------------------------------------------------------------------
// Conv v4: balanced triangular GEMM, A-fragments direct from L2 (no A LDS),
// double-buffered P, ONE barrier per K-step, h-major XCD chunking.
//   wid = bx + 8*b + 64*h ; chunked swizzle -> XCD owns 2 heads
//   (Mf WS 1MB + H1 WS 4MB per XCD).
// Output tile 128u x 64d, 4 waves (32u x 64d each), acc[2][4].
// ---------------------------------------------------------------------------
__global__ void conv4_k(const unsigned short* __restrict__ H1,   // (B,DIM,T) bf16
                        const unsigned short* __restrict__ Mf,   // (H,32,8,128,8) bf16
                        const float* __restrict__ tb,            // (H,T) f32
                        unsigned short* __restrict__ Cb) {       // (B,T,DIM) bf16
    __shared__ __align__(16) unsigned short Ps[2][64 * 64];

    const int flat = blockIdx.x;                 // 1024 blocks
    const int wid  = (flat & 7) * 128 + (flat >> 3);
    const int bx   = wid & 7;
    const int b    = (wid >> 3) & 7;
    const int h    = wid >> 6;

    const int tid = threadIdx.x, lane = tid & 63, wv = tid >> 6;
    const unsigned short* Hb = H1 + ((size_t)b * DIM + h * HD) * T_;
    const unsigned short* Ah = Mf + ((size_t)h * 32) * 8192;

    const int lrow = lane & 15, lg = lane >> 4;
    const int rsub = lane >> 3;
    const int g = (lane & 7) ^ rsub;

    // lane-constant part of the A-fragment offset (elems)
    const int aoff = (lg * 128 + wv * 32 + lrow) * 8;

#pragma unroll
    for (int ph = 0; ph < 2; ++ph) {
        const int ut = ph ? bx : (T_ / 128 - 1 - bx);
        const int u0 = ut * 128;
        const int nk = 2 * ut + 2;
        f32x4 acc[2][4] = {};

        // prologue: stage P(kt=0) into buf 0
#pragma unroll
        for (int it = 0; it < 2; ++it) {
            int ch = wv * 2 + it;
            int r  = ch * 8 + rsub;
            gl_lds16(Hb + (size_t)r * T_ + g * 8, &Ps[0][0] + ch * 512);
        }
        __syncthreads();

        for (int kt = 0; kt < nk; ++kt) {
            const int cur = kt & 1;
            // stage next P tile into the other buffer (issued before compute)
            if (kt + 1 < nk) {
                const int t0n = (kt + 1) * 64;
#pragma unroll
                for (int it = 0; it < 2; ++it) {
                    int ch = wv * 2 + it;
                    int r  = ch * 8 + rsub;
                    gl_lds16(Hb + (size_t)r * T_ + t0n + g * 8, &Ps[cur ^ 1][0] + ch * 512);
                }
            }
            // A fragments straight from L2 (fragment-layout Mf)
            const int dg = 2 * ut - kt + 1;
            const unsigned short* At = Ah + (size_t)dg * 8192;
            bf16x8 af0[2], af1[2];
#pragma unroll
            for (int mt = 0; mt < 2; ++mt) {
                af0[mt] = *reinterpret_cast<const bf16x8*>(At + aoff + mt * 128);
                af1[mt] = *reinterpret_cast<const bf16x8*>(At + 4096 + aoff + mt * 128);
            }
            const unsigned short* Pb = &Ps[cur][0];
            bf16x8 bfr[4];
#pragma unroll
            for (int nt = 0; nt < 4; ++nt) bfr[nt] = ld_frag(Pb, nt * 16 + lrow, lg);
#pragma unroll
            for (int mt = 0; mt < 2; ++mt)
#pragma unroll
                for (int nt = 0; nt < 4; ++nt)
                    acc[mt][nt] = __builtin_amdgcn_mfma_f32_16x16x32_bf16(af0[mt], bfr[nt], acc[mt][nt], 0, 0, 0);
#pragma unroll
            for (int nt = 0; nt < 4; ++nt) bfr[nt] = ld_frag(Pb, nt * 16 + lrow, 4 + lg);
#pragma unroll
            for (int mt = 0; mt < 2; ++mt)
#pragma unroll
                for (int nt = 0; nt < 4; ++nt)
                    acc[mt][nt] = __builtin_amdgcn_mfma_f32_16x16x32_bf16(af1[mt], bfr[nt], acc[mt][nt], 0, 0, 0);

            __syncthreads();   // drains this wave's staging loads, then barrier
        }

        // epilogue -> C (B,T,DIM)
        const size_t base = (size_t)b * T_ * DIM + (size_t)h * HD;
#pragma unroll
        for (int mt = 0; mt < 2; ++mt) {
            int u = u0 + wv * 32 + mt * 16 + lg * 4;
            const float* tbp = tb + h * T_ + u;
            float t0v = tbp[0], t1v = tbp[1], t2v = tbp[2], t3v = tbp[3];
#pragma unroll
            for (int nt = 0; nt < 4; ++nt) {
                int d = nt * 16 + lrow;
                size_t p = base + (size_t)u * DIM + d;
                Cb[p]           = f2bf(acc[mt][nt][0] + t0v);
                Cb[p + DIM]     = f2bf(acc[mt][nt][1] + t1v);
                Cb[p + 2 * DIM] = f2bf(acc[mt][nt][2] + t2v);
                Cb[p + 3 * DIM] = f2bf(acc[mt][nt][3] + t3v);
            }
        }
    }
}

// ---------------------------------------------------------------------------
extern "C" void kernel_launch(void* const* d_in, const int* in_sizes, int n_in,
                              void* d_out, int out_size, void* d_ws, size_t ws_size,
                              hipStream_t stream) {
    (void)in_sizes; (void)n_in; (void)out_size; (void)ws_size;
    const float* x      = (const float*)d_in[0];
    const float* w_in   = (const float*)d_in[1];
    const float* b_in   = (const float*)d_in[2];
    const float* w_out  = (const float*)d_in[3];
    const float* b_out  = (const float*)d_in[4];
    const float* toep_w = (const float*)d_in[5];
    const float* toep_b = (const float*)d_in[6];

    char* ws = (char*)d_ws;
    unsigned short* XT    = (unsigned short*)(ws);                 // 32 MiB (B,T,DIM) bf16
    unsigned short* H1    = (unsigned short*)(ws + 33554432);      // 32 MiB (B,DIM,T) bf16
    unsigned short* Cbuf  = (unsigned short*)(ws + 67108864);      // 32 MiB (B,T,DIM) bf16
    unsigned short* winb  = (unsigned short*)(ws + 100663296);     // 2 MiB
    unsigned short* woutb = (unsigned short*)(ws + 102760448);     // 2 MiB
    unsigned short* twb   = (unsigned short*)(ws + 104857600);     // 64 KiB
    unsigned short* Mfrag = (unsigned short*)(ws + 104923136);     // 8 MiB (H,32,8,128,8)

    xpose_cast<<<dim3(T_ / 64, DIM / 64, B_), dim3(256), 0, stream>>>(x, XT);
    cast_weights<<<dim3((DIM * DIM) / 256), dim3(256), 0, stream>>>(w_in, w_out, toep_w, winb, woutb, twb);
    gen_mfrag<<<dim3(32, H_), dim3(256), 0, stream>>>(twb, Mfrag);
    gemm_k<true><<<dim3(1024), dim3(256), 0, stream>>>(winb, XT, b_in, (void*)H1);
    conv4_k<<<dim3(1024), dim3(256), 0, stream>>>(H1, Mfrag, toep_b, Cbuf);
    gemm_k<false><<<dim3(1024), dim3(256), 0, stream>>>(woutb, Cbuf, b_out, d_out);
}